// Round 14
// baseline (241.395 us; speedup 1.0000x reference)
//
#include <hip/hip_runtime.h>
#include <hip/hip_bf16.h>

typedef __bf16 bf16x8 __attribute__((ext_vector_type(8)));
typedef __bf16 bf16x4 __attribute__((ext_vector_type(4)));
typedef float  f32x4  __attribute__((ext_vector_type(4)));

#define NN   20000
#define NADJ 17

// bijective XCD-aware remap: blocks with the same row-group land on the SAME XCD,
// adjacent in dispatch order -> A-tile L2 reuse across column blocks.
__device__ __forceinline__ void xcd_remap(int b, int nwg, int col_shift, int& r, int& c)
{
    int q = nwg >> 3, rem = nwg & 7;
    int x = b & 7, k = b >> 3;
    int start = x * q + (x < rem ? x : rem);
    int idx = start + k;
    r = idx >> col_shift;
    c = idx & ((1 << col_shift) - 1);
}

// Wb layout (bf16):
//   [0]        Win   256 rows x 256   (x0 GEMM)
//   [65536]    Wps   256 rows x 512   = [Wp | Wn]         (summary GEMM, K=512)
//   [196608]   Wcat 1024 rows x 512   GRU fused weights   (row c: j=(c>>6)*16+(c&15), g=(c>>4)&3)
// bc layout (f32): [0:256) bin | [256:512) bp+bn | [512:1536) bcat
// Fused pack: blocks [0,704) pack weights+biases; blocks [704,5704) pack info.
__global__ void pack_all_kernel(const float* __restrict__ Win, const float* __restrict__ bin,
                                const float* __restrict__ Wp,  const float* __restrict__ bp,
                                const float* __restrict__ Wn,  const float* __restrict__ bn,
                                const float* __restrict__ Wih, const float* __restrict__ bih,
                                const float* __restrict__ Whh, const float* __restrict__ bhh,
                                const float* __restrict__ names, const float* __restrict__ attrs,
                                __bf16* __restrict__ Wb, float* __restrict__ bc,
                                __bf16* __restrict__ xb)
{
    if (blockIdx.x >= 704) {
        int idx = (blockIdx.x - 704) * 256 + threadIdx.x;   // NN*64 threads, 4 elems each
        if (idx >= NN * 64) return;
        int i  = idx >> 6;
        int d4 = (idx & 63) << 2;
        const float* src = (d4 < 128) ? (names + (size_t)i * 128 + d4)
                                      : (attrs + (size_t)i * 128 + (d4 - 128));
        float4 v = *(const float4*)src;
        bf16x4 o = { (__bf16)v.x, (__bf16)v.y, (__bf16)v.z, (__bf16)v.w };
        *(bf16x4*)(xb + (size_t)i * 256 + d4) = o;
        return;
    }
    int idx = blockIdx.x * 256 + threadIdx.x;   // 704*256 = 180224 threads, 4 bf16 each
    if (idx < 1536) {
        int c = idx; float v;
        if (c < 256)      v = bin[c];
        else if (c < 512) { int j = c - 256; v = bp[j] + bn[j]; }
        else {
            int rel = c - 512;
            int j = (rel >> 6) * 16 + (rel & 15);
            int g = (rel >> 4) & 3;
            if      (g == 0) v = bih[j] + bhh[j];
            else if (g == 1) v = bih[256 + j] + bhh[256 + j];
            else if (g == 2) v = bih[512 + j];
            else             v = bhh[512 + j];
        }
        bc[c] = v;
    }
    int e = idx << 2;                           // element offset in Wb
    const float* src = nullptr;
    bool zero = false;
    if (e < 65536) {
        int row = e >> 8, k = e & 255;
        src = Win + (size_t)row * 256 + k;
    } else if (e < 196608) {
        int rel = e - 65536;
        int row = rel >> 9, k = rel & 511;
        src = (k < 256) ? (Wp + (size_t)row * 256 + k)
                        : (Wn + (size_t)row * 256 + (k - 256));
    } else {
        int rel = e - 196608;
        int row = rel >> 9, k = rel & 511;
        int j = (row >> 6) * 16 + (row & 15);
        int g = (row >> 4) & 3;
        if (k < 256) {
            if (g == 3) zero = true;
            else {
                int off = (g == 0) ? 0 : (g == 1) ? 256 : 512;
                src = Wih + (size_t)(off + j) * 256 + k;
            }
        } else {
            int k2 = k - 256;
            if (g == 2) zero = true;
            else {
                int off = (g == 0) ? 0 : (g == 1) ? 256 : 512;
                src = Whh + (size_t)(off + j) * 256 + k2;
            }
        }
    }
    float4 v = zero ? make_float4(0.f, 0.f, 0.f, 0.f) : *(const float4*)src;
    bf16x4 o = { (__bf16)v.x, (__bf16)v.y, (__bf16)v.z, (__bf16)v.w };
    *(bf16x4*)(Wb + (size_t)e) = o;
}

// ---------------------------------------------------------------- gather: G2 = avg_j x[nbr_j]  (N x 256 bf16)
// 2 nodes per wave: each 32-lane half owns one node's 512B row, 16B (bf16x8) per lane.
__global__ void gather_avg_kernel(const int* __restrict__ adj, const __bf16* __restrict__ x,
                                  __bf16* __restrict__ G2)
{
    const int l  = threadIdx.x & 63;
    const int w  = threadIdx.x >> 6;
    const int lh = l & 31;                                  // lane-in-half
    const int node = blockIdx.x * 8 + w * 2 + (l >> 5);     // 8 nodes/block
    int av = (lh < NADJ) ? adj[(size_t)node * NADJ + lh] : -1;
    float s[8] = {0.f, 0.f, 0.f, 0.f, 0.f, 0.f, 0.f, 0.f};
    int cnt = 0;
#pragma unroll
    for (int j = 1; j < NADJ; ++j) {
        int idx = __shfl(av, (l & 32) + j, 64);             // broadcast within own half
        if (idx >= 0) {
            ++cnt;
            bf16x8 v = *(const bf16x8*)(x + (size_t)idx * 256 + lh * 8);
#pragma unroll
            for (int u = 0; u < 8; ++u) s[u] += (float)v[u];
        }
    }
    float inv = 1.f / (float)(cnt < 1 ? 1 : cnt);
    bf16x8 o;
#pragma unroll
    for (int u = 0; u < 8; ++u) o[u] = (__bf16)(s[u] * inv);
    *(bf16x8*)(G2 + (size_t)node * 256 + lh * 8) = o;
}

// pipeline barrier helpers: raw s_barrier (NO implicit vmcnt drain) sandwiched by
// memory clobbers so the compiler cannot move LDS accesses across it.
#define PIPE_BARRIER()                                \
    do {                                              \
        asm volatile("" ::: "memory");                \
        __builtin_amdgcn_s_barrier();                 \
        asm volatile("" ::: "memory");                \
    } while (0)

// ---------------------------------------------------------------- generic GEMM  C = A * W^T + bias
// 128x128 tile, BK=64, 512 threads = 8 waves (4x2 wave grid, wave tile 32x64).
// Double-buffered with COUNTED vmcnt (T4): stage(kt+1) before compute(kt);
// s_waitcnt vmcnt(4) + raw s_barrier; vmcnt(0) only at the last kt.
// Flat grid + XCD remap. A half 0 (k<256): if parents != null, row r reads A0[parents[r]], else A0[r].
// A half 1 (k>=256, only if A1 != null): A1[r] stride 256.
// Output: Cb = bf16(v); if Cl != null also lo = bf16(v - hi)  (hi/lo split).
__global__ __launch_bounds__(512, 4)
void gemm_bias_kernel(const __bf16* __restrict__ A0, const __bf16* __restrict__ A1, int lda,
                      const int* __restrict__ parents, int par_stride,
                      const __bf16* __restrict__ W, int ldw,
                      const float* __restrict__ bias,
                      __bf16* __restrict__ Cb, __bf16* __restrict__ Cl,
                      int n_rows, int n_cols, int kt_n, int nwg, int col_shift)
{
    __shared__ __align__(16) __bf16 As[2][128 * 64];
    __shared__ __align__(16) __bf16 Bs[2][128 * 64];
    __shared__ int par_s[128];
    const int t = threadIdx.x;
    const int w = t >> 6;
    const int l = t & 63;
    int rb, cb_;
    xcd_remap(blockIdx.x, nwg, col_shift, rb, cb_);
    const int brow = rb * 128;
    const int bcol = cb_ * 128;
    const int wr = (w >> 1) * 32, wc = (w & 1) * 64;

    if (parents) {
        if (t < 128) {
            int node = brow + t; if (node > n_rows - 1) node = n_rows - 1;
            par_s[t] = parents[(size_t)node * par_stride];
        }
        __syncthreads();
    }

    auto stage = [&](int kt, int buf) {
        const int k0 = kt * 64;
        // A: 128x64 = 2 issues/thread
#pragma unroll
        for (int i = 0; i < 2; ++i) {
            int f   = i * 512 + t;
            int row = f >> 3;
            int cs  = ((f & 7) * 16) ^ ((row & 7) << 4);
            int ar  = brow + row; if (ar > n_rows - 1) ar = n_rows - 1;
            const __bf16* abase;
            if (parents && k0 < 256)             abase = A0 + (size_t)par_s[row] * 256 + k0;
            else if (A1 != nullptr && k0 >= 256) abase = A1 + (size_t)ar * 256 + (k0 - 256);
            else                                 abase = A0 + (size_t)ar * lda + k0;
            const __bf16* ga = abase + (cs >> 1);
            char* la = (char*)As[buf] + (i * 512 + w * 64) * 16;
            __builtin_amdgcn_global_load_lds(
                (const __attribute__((address_space(1))) unsigned int*)ga,
                (__attribute__((address_space(3))) unsigned int*)la, 16, 0, 0);
        }
        // B: 128x64 = 2 issues/thread
#pragma unroll
        for (int i = 0; i < 2; ++i) {
            int f   = i * 512 + t;
            int row = f >> 3;
            int cs  = ((f & 7) * 16) ^ ((row & 7) << 4);
            const __bf16* gb = W + (size_t)(bcol + row) * ldw + k0 + (cs >> 1);
            char* lb = (char*)Bs[buf] + (i * 512 + w * 64) * 16;
            __builtin_amdgcn_global_load_lds(
                (const __attribute__((address_space(1))) unsigned int*)gb,
                (__attribute__((address_space(3))) unsigned int*)lb, 16, 0, 0);
        }
    };

    f32x4 acc[2][4] = {};
    stage(0, 0);

    for (int kt = 0; kt < kt_n; ++kt) {
        const int buf = kt & 1;
        if (kt + 1 < kt_n) {
            stage(kt + 1, buf ^ 1);
            asm volatile("s_waitcnt vmcnt(4)" ::: "memory");   // kt's 4 loads retired
        } else {
            asm volatile("s_waitcnt vmcnt(0)" ::: "memory");
        }
        PIPE_BARRIER();
#pragma unroll
        for (int ks = 0; ks < 2; ++ks) {
            bf16x8 af[2], bfv[4];
#pragma unroll
            for (int m = 0; m < 2; ++m) {
                int row = wr + m * 16 + (l & 15);
                int cb  = (ks * 64 + ((l >> 4) * 16)) ^ ((row & 7) << 4);
                af[m] = *(const bf16x8*)((const char*)As[buf] + row * 128 + cb);
            }
#pragma unroll
            for (int n = 0; n < 4; ++n) {
                int row = wc + n * 16 + (l & 15);
                int cb  = (ks * 64 + ((l >> 4) * 16)) ^ ((row & 7) << 4);
                bfv[n] = *(const bf16x8*)((const char*)Bs[buf] + row * 128 + cb);
            }
#pragma unroll
            for (int m = 0; m < 2; ++m)
#pragma unroll
                for (int n = 0; n < 4; ++n)
                    acc[m][n] = __builtin_amdgcn_mfma_f32_16x16x32_bf16(af[m], bfv[n], acc[m][n], 0, 0, 0);
        }
        PIPE_BARRIER();   // all reads of buf done before it is overwritten next iter
    }
    // epilogue: C/D mapping col = lane&15, row = (lane>>4)*4 + reg
#pragma unroll
    for (int m = 0; m < 2; ++m) {
        int r0 = brow + wr + m * 16 + ((l >> 4) * 4);
#pragma unroll
        for (int n = 0; n < 4; ++n) {
            int c = bcol + wc + n * 16 + (l & 15);
            float bv = bias[c];
#pragma unroll
            for (int i = 0; i < 4; ++i) {
                int r = r0 + i;
                if (r < n_rows) {
                    float v = acc[m][n][i] + bv;
                    __bf16 hi = (__bf16)v;
                    Cb[(size_t)r * n_cols + c] = hi;
                    if (Cl) Cl[(size_t)r * n_cols + c] = (__bf16)(v - (float)hi);
                }
            }
        }
    }
}

// ---------------------------------------------------------------- fused GRU GEMM (persistent counted-vmcnt dbuf)
// 128x128 tile, 512 threads, 8 waves. Grid = 512 persistent blocks (2/CU, all co-resident);
// block b processes tiles b, b+512, b+1024 with a CONTINUOUS pipeline: global step
// g = tile*8 + kt; stage(g+1) always issued before compute(g); epilogue at kt==7 runs
// while the next tile's kt=0 loads are in flight. Tiles of one block stay on one XCD
// slice ((b+512j)&7 == b&7), preserving the remap's L2 locality.
// A = [xb | sbh] (K=512 split). W = Wcat (1024 x 512): out-col c -> j=(c>>6)*16+(c&15),
// gate=(c>>4)&3. gates: 0 = i_r+h_r, 1 = i_z+h_z, 2 = i_n (k<256), 3 = h_n (k>=256).
// B staged unconditionally; MFMA for the dead gate block skipped.
__global__ __launch_bounds__(512, 4)
void gru_gemm_kernel(const __bf16* __restrict__ A0, const __bf16* __restrict__ A1,
                     const __bf16* __restrict__ W,
                     const float* __restrict__ bias,
                     const __bf16* __restrict__ sbh, const __bf16* __restrict__ sbl,
                     float* __restrict__ X, __bf16* __restrict__ xb_next,
                     int n_rows)
{
    __shared__ __align__(16) __bf16 As[2][128 * 64];
    __shared__ __align__(16) __bf16 Bs[2][128 * 64];
    const int t = threadIdx.x;
    const int w = t >> 6;
    const int l = t & 63;
    const int wr = (w >> 1) * 32, wc = (w & 1) * 64;

    int browA[3], bcolA[3];
    int nt = 0;
    for (int tt = blockIdx.x; tt < 157 * 8; tt += 512) {
        int rb, cb_;
        xcd_remap(tt, 157 * 8, 3, rb, cb_);
        browA[nt] = rb * 128;
        bcolA[nt] = cb_ * 128;
        ++nt;
    }

    auto stage = [&](int ti, int kt, int buf) {
        const int k0 = kt * 64;
        const int brow = browA[ti], bcol = bcolA[ti];
        const __bf16* ab = (kt < 4) ? (A0 + k0) : (A1 + (k0 - 256));
        // A: 2 issues/thread
#pragma unroll
        for (int i = 0; i < 2; ++i) {
            int f   = i * 512 + t;
            int row = f >> 3;
            int cs  = ((f & 7) * 16) ^ ((row & 7) << 4);
            int ar  = brow + row; if (ar > n_rows - 1) ar = n_rows - 1;
            const __bf16* ga = ab + (size_t)ar * 256 + (cs >> 1);
            char* la = (char*)As[buf] + (i * 512 + w * 64) * 16;
            __builtin_amdgcn_global_load_lds(
                (const __attribute__((address_space(1))) unsigned int*)ga,
                (__attribute__((address_space(3))) unsigned int*)la, 16, 0, 0);
        }
        // B: 2 issues/thread (unconditional -> uniform vmcnt)
#pragma unroll
        for (int i = 0; i < 2; ++i) {
            int f   = i * 512 + t;
            int row = f >> 3;
            int cs  = ((f & 7) * 16) ^ ((row & 7) << 4);
            const __bf16* gb = W + (size_t)(bcol + row) * 512 + k0 + (cs >> 1);
            char* lb = (char*)Bs[buf] + (i * 512 + w * 64) * 16;
            __builtin_amdgcn_global_load_lds(
                (const __attribute__((address_space(1))) unsigned int*)gb,
                (__attribute__((address_space(3))) unsigned int*)lb, 16, 0, 0);
        }
    };

    f32x4 acc[2][4] = {};
    const int total = nt * 8;
    stage(0, 0, 0);

    for (int g = 0; g < total; ++g) {
        const int buf = g & 1;
        const int kt  = g & 7;
        const int ti  = g >> 3;
        const int skipn = (kt < 4) ? 3 : 2;
        if (g + 1 < total) {
            stage((g + 1) >> 3, (g + 1) & 7, buf ^ 1);
            asm volatile("s_waitcnt vmcnt(4)" ::: "memory");
        } else {
            asm volatile("s_waitcnt vmcnt(0)" ::: "memory");
        }
        PIPE_BARRIER();
#pragma unroll
        for (int ks = 0; ks < 2; ++ks) {
            bf16x8 af[2], bfv[4];
#pragma unroll
            for (int m = 0; m < 2; ++m) {
                int row = wr + m * 16 + (l & 15);
                int cb  = (ks * 64 + ((l >> 4) * 16)) ^ ((row & 7) << 4);
                af[m] = *(const bf16x8*)((const char*)As[buf] + row * 128 + cb);
            }
#pragma unroll
            for (int n = 0; n < 4; ++n) {
                if (n == skipn) continue;
                int row = wc + n * 16 + (l & 15);
                int cb  = (ks * 64 + ((l >> 4) * 16)) ^ ((row & 7) << 4);
                bfv[n] = *(const bf16x8*)((const char*)Bs[buf] + row * 128 + cb);
            }
#pragma unroll
            for (int m = 0; m < 2; ++m)
#pragma unroll
                for (int n = 0; n < 4; ++n)
                    if (n != skipn)
                        acc[m][n] = __builtin_amdgcn_mfma_f32_16x16x32_bf16(af[m], bfv[n], acc[m][n], 0, 0, 0);
        }
        PIPE_BARRIER();

        if (kt == 7) {
            // GRU epilogue for tile ti (runs while next tile's kt=0 loads are in flight)
            const int brow = browA[ti], bcol = bcolA[ti];
            const int jb = ((bcol + wc) >> 6) * 16 + (l & 15);
            const int c0 = bcol + wc + (l & 15);
            const float b0 = bias[c0], b1 = bias[c0 + 16], b2 = bias[c0 + 32], b3 = bias[c0 + 48];
#pragma unroll
            for (int m = 0; m < 2; ++m) {
                int r0 = brow + wr + m * 16 + ((l >> 4) * 4);
#pragma unroll
                for (int i = 0; i < 4; ++i) {
                    int r = r0 + i;
                    if (r < n_rows) {
                        float gr  = acc[m][0][i] + b0;
                        float gz  = acc[m][1][i] + b1;
                        float gin = acc[m][2][i] + b2;
                        float ghn = acc[m][3][i] + b3;
                        float rg = 1.f / (1.f + __expf(-gr));
                        float zg = 1.f / (1.f + __expf(-gz));
                        float a2 = gin + rg * ghn;
                        float tt = __expf(-2.f * fabsf(a2));
                        float ng = (1.f - tt) / (1.f + tt);
                        ng = (a2 < 0.f) ? -ng : ng;
                        float h = (float)sbh[(size_t)r * 256 + jb] + (float)sbl[(size_t)r * 256 + jb];
                        float out = (1.f - zg) * ng + zg * h;
                        if (X)       X[(size_t)r * 256 + jb] = out;
                        if (xb_next) xb_next[(size_t)r * 256 + jb] = (__bf16)out;
                    }
                }
            }
#pragma unroll
            for (int m = 0; m < 2; ++m)
#pragma unroll
                for (int n = 0; n < 4; ++n)
                    acc[m][n] = (f32x4){0.f, 0.f, 0.f, 0.f};
        }
    }
}

// ---------------------------------------------------------------- launch
extern "C" void kernel_launch(void* const* d_in, const int* in_sizes, int n_in,
                              void* d_out, int out_size, void* d_ws, size_t ws_size,
                              hipStream_t stream)
{
    const int*   adj   = (const int*)  d_in[0];
    const float* names = (const float*)d_in[1];
    const float* attrs = (const float*)d_in[2];
    const float* Win = (const float*)d_in[3];
    const float* bin = (const float*)d_in[4];
    const float* Wp  = (const float*)d_in[5];
    const float* bp  = (const float*)d_in[6];
    const float* Wn  = (const float*)d_in[7];
    const float* bn  = (const float*)d_in[8];
    const float* Wih = (const float*)d_in[9];
    const float* bih = (const float*)d_in[10];
    const float* Whh = (const float*)d_in[11];
    const float* bhh = (const float*)d_in[12];
    float* X = (float*)d_out;

    // workspace layout
    char* w = (char*)d_ws;
    __bf16* xinfo = (__bf16*)(w);                // N x 256 bf16   10,240,000
    __bf16* xb0   = (__bf16*)(w + 10240000);     // N x 256 bf16
    __bf16* xb1   = (__bf16*)(w + 20480000);     // N x 256 bf16
    __bf16* sbh   = (__bf16*)(w + 30720000);     // N x 256 bf16
    __bf16* sbl   = (__bf16*)(w + 40960000);     // N x 256 bf16
    __bf16* G2    = (__bf16*)(w + 51200000);     // N x 256 bf16
    __bf16* Wb    = (__bf16*)(w + 61440000);     // 720896 bf16     1,441,792
    float*  bc    = (float*) (w + 62881792);     // 1536 f32

    pack_all_kernel<<<5704, 256, 0, stream>>>(Win, bin, Wp, bp, Wn, bn, Wih, bih, Whh, bhh,
                                              names, attrs, Wb, bc, xinfo);

    // x0 = info @ Win^T + bin  -> bf16 only   (314 = 157 row-blocks x 2 col-blocks)
    gemm_bias_kernel<<<314, 512, 0, stream>>>(xinfo, nullptr, 256, nullptr, 0,
                                              Wb, 256, bc, xb0, nullptr, NN, 256, 4, 314, 1);

    __bf16* cur = xb0;
    __bf16* nxt = xb1;
    for (int d = 0; d < 3; ++d) {
        gather_avg_kernel<<<2500, 256, 0, stream>>>(adj, cur, G2);
        // summary = [x[parent] | avg] @ [Wp|Wn]^T + (bp+bn): parent half gathered in-staging,
        // output as hi/lo bf16 split
        gemm_bias_kernel<<<314, 512, 0, stream>>>(cur, G2, 256, adj, NADJ,
                                                  Wb + 65536, 512, bc + 256,
                                                  sbh, sbl, NN, 256, 8, 314, 1);
        // fused GRU: [cur|sbh] @ Wcat^T, persistent grid (512 blocks, 2/CU)
        gru_gemm_kernel<<<512, 512, 0, stream>>>(cur, sbh, Wb + 196608, bc + 512,
                                                 sbh, sbl, (d == 2) ? X : nullptr,
                                                 (d < 2) ? nxt : nullptr, NN);
        __bf16* tmp = cur; cur = nxt; nxt = tmp;
    }
}

// Round 15
// 219.384 us; speedup vs baseline: 1.1003x; 1.1003x over previous
//
#include <hip/hip_runtime.h>
#include <hip/hip_bf16.h>

typedef __bf16 bf16x8 __attribute__((ext_vector_type(8)));
typedef __bf16 bf16x4 __attribute__((ext_vector_type(4)));
typedef float  f32x4  __attribute__((ext_vector_type(4)));

#define NN   20000
#define NADJ 17

// bijective XCD-aware remap: blocks with the same row-group land on the SAME XCD,
// adjacent in dispatch order -> A-tile L2 reuse across column blocks.
__device__ __forceinline__ void xcd_remap(int b, int nwg, int col_shift, int& r, int& c)
{
    int q = nwg >> 3, rem = nwg & 7;
    int x = b & 7, k = b >> 3;
    int start = x * q + (x < rem ? x : rem);
    int idx = start + k;
    r = idx >> col_shift;
    c = idx & ((1 << col_shift) - 1);
}

// Wb layout (bf16):
//   [0]        Win   256 rows x 256   (x0 GEMM)
//   [65536]    Wps   256 rows x 512   = [Wp | Wn]         (summary GEMM, K=512)
//   [196608]   Wcat 1024 rows x 512   GRU fused weights   (row c: j=(c>>6)*16+(c&15), g=(c>>4)&3)
// bc layout (f32): [0:256) bin | [256:512) bp+bn | [512:1536) bcat
// Fused pack: blocks [0,704) pack weights+biases; blocks [704,5704) pack info.
__global__ void pack_all_kernel(const float* __restrict__ Win, const float* __restrict__ bin,
                                const float* __restrict__ Wp,  const float* __restrict__ bp,
                                const float* __restrict__ Wn,  const float* __restrict__ bn,
                                const float* __restrict__ Wih, const float* __restrict__ bih,
                                const float* __restrict__ Whh, const float* __restrict__ bhh,
                                const float* __restrict__ names, const float* __restrict__ attrs,
                                __bf16* __restrict__ Wb, float* __restrict__ bc,
                                __bf16* __restrict__ xb)
{
    if (blockIdx.x >= 704) {
        int idx = (blockIdx.x - 704) * 256 + threadIdx.x;   // NN*64 threads, 4 elems each
        if (idx >= NN * 64) return;
        int i  = idx >> 6;
        int d4 = (idx & 63) << 2;
        const float* src = (d4 < 128) ? (names + (size_t)i * 128 + d4)
                                      : (attrs + (size_t)i * 128 + (d4 - 128));
        float4 v = *(const float4*)src;
        bf16x4 o = { (__bf16)v.x, (__bf16)v.y, (__bf16)v.z, (__bf16)v.w };
        *(bf16x4*)(xb + (size_t)i * 256 + d4) = o;
        return;
    }
    int idx = blockIdx.x * 256 + threadIdx.x;   // 704*256 = 180224 threads, 4 bf16 each
    if (idx < 1536) {
        int c = idx; float v;
        if (c < 256)      v = bin[c];
        else if (c < 512) { int j = c - 256; v = bp[j] + bn[j]; }
        else {
            int rel = c - 512;
            int j = (rel >> 6) * 16 + (rel & 15);
            int g = (rel >> 4) & 3;
            if      (g == 0) v = bih[j] + bhh[j];
            else if (g == 1) v = bih[256 + j] + bhh[256 + j];
            else if (g == 2) v = bih[512 + j];
            else             v = bhh[512 + j];
        }
        bc[c] = v;
    }
    int e = idx << 2;                           // element offset in Wb
    const float* src = nullptr;
    bool zero = false;
    if (e < 65536) {
        int row = e >> 8, k = e & 255;
        src = Win + (size_t)row * 256 + k;
    } else if (e < 196608) {
        int rel = e - 65536;
        int row = rel >> 9, k = rel & 511;
        src = (k < 256) ? (Wp + (size_t)row * 256 + k)
                        : (Wn + (size_t)row * 256 + (k - 256));
    } else {
        int rel = e - 196608;
        int row = rel >> 9, k = rel & 511;
        int j = (row >> 6) * 16 + (row & 15);
        int g = (row >> 4) & 3;
        if (k < 256) {
            if (g == 3) zero = true;
            else {
                int off = (g == 0) ? 0 : (g == 1) ? 256 : 512;
                src = Wih + (size_t)(off + j) * 256 + k;
            }
        } else {
            int k2 = k - 256;
            if (g == 2) zero = true;
            else {
                int off = (g == 0) ? 0 : (g == 1) ? 256 : 512;
                src = Whh + (size_t)(off + j) * 256 + k2;
            }
        }
    }
    float4 v = zero ? make_float4(0.f, 0.f, 0.f, 0.f) : *(const float4*)src;
    bf16x4 o = { (__bf16)v.x, (__bf16)v.y, (__bf16)v.z, (__bf16)v.w };
    *(bf16x4*)(Wb + (size_t)e) = o;
}

// ---------------------------------------------------------------- gather: G2 = avg_j x[nbr_j]  (N x 256 bf16)
// 2 nodes per wave: each 32-lane half owns one node's 512B row, 16B (bf16x8) per lane.
__global__ void gather_avg_kernel(const int* __restrict__ adj, const __bf16* __restrict__ x,
                                  __bf16* __restrict__ G2)
{
    const int l  = threadIdx.x & 63;
    const int w  = threadIdx.x >> 6;
    const int lh = l & 31;                                  // lane-in-half
    const int node = blockIdx.x * 8 + w * 2 + (l >> 5);     // 8 nodes/block
    int av = (lh < NADJ) ? adj[(size_t)node * NADJ + lh] : -1;
    float s[8] = {0.f, 0.f, 0.f, 0.f, 0.f, 0.f, 0.f, 0.f};
    int cnt = 0;
#pragma unroll
    for (int j = 1; j < NADJ; ++j) {
        int idx = __shfl(av, (l & 32) + j, 64);             // broadcast within own half
        if (idx >= 0) {
            ++cnt;
            bf16x8 v = *(const bf16x8*)(x + (size_t)idx * 256 + lh * 8);
#pragma unroll
            for (int u = 0; u < 8; ++u) s[u] += (float)v[u];
        }
    }
    float inv = 1.f / (float)(cnt < 1 ? 1 : cnt);
    bf16x8 o;
#pragma unroll
    for (int u = 0; u < 8; ++u) o[u] = (__bf16)(s[u] * inv);
    *(bf16x8*)(G2 + (size_t)node * 256 + lh * 8) = o;
}

// pipeline barrier helpers: raw s_barrier (NO implicit vmcnt drain) sandwiched by
// memory clobbers so the compiler cannot move LDS accesses across it.
#define PIPE_BARRIER()                                \
    do {                                              \
        asm volatile("" ::: "memory");                \
        __builtin_amdgcn_s_barrier();                 \
        asm volatile("" ::: "memory");                \
    } while (0)

// ---------------------------------------------------------------- generic GEMM  C = A * W^T + bias
// 128x128 tile, BK=64, 512 threads = 8 waves (4x2 wave grid, wave tile 32x64).
// Double-buffered with COUNTED vmcnt (T4): stage(kt+1) before compute(kt);
// s_waitcnt vmcnt(4) + raw s_barrier; vmcnt(0) only at the last kt.
// Flat grid + XCD remap. A half 0 (k<256): if parents != null, row r reads A0[parents[r]], else A0[r].
// A half 1 (k>=256, only if A1 != null): A1[r] stride 256.
// Output: Cb = bf16(v); if Cl != null also lo = bf16(v - hi)  (hi/lo split).
__global__ __launch_bounds__(512, 4)
void gemm_bias_kernel(const __bf16* __restrict__ A0, const __bf16* __restrict__ A1, int lda,
                      const int* __restrict__ parents, int par_stride,
                      const __bf16* __restrict__ W, int ldw,
                      const float* __restrict__ bias,
                      __bf16* __restrict__ Cb, __bf16* __restrict__ Cl,
                      int n_rows, int n_cols, int kt_n, int nwg, int col_shift)
{
    __shared__ __align__(16) __bf16 As[2][128 * 64];
    __shared__ __align__(16) __bf16 Bs[2][128 * 64];
    __shared__ int par_s[128];
    const int t = threadIdx.x;
    const int w = t >> 6;
    const int l = t & 63;
    int rb, cb_;
    xcd_remap(blockIdx.x, nwg, col_shift, rb, cb_);
    const int brow = rb * 128;
    const int bcol = cb_ * 128;
    const int wr = (w >> 1) * 32, wc = (w & 1) * 64;

    if (parents) {
        if (t < 128) {
            int node = brow + t; if (node > n_rows - 1) node = n_rows - 1;
            par_s[t] = parents[(size_t)node * par_stride];
        }
        __syncthreads();
    }

    auto stage = [&](int kt, int buf) {
        const int k0 = kt * 64;
        // A: 128x64 = 2 issues/thread
#pragma unroll
        for (int i = 0; i < 2; ++i) {
            int f   = i * 512 + t;
            int row = f >> 3;
            int cs  = ((f & 7) * 16) ^ ((row & 7) << 4);
            int ar  = brow + row; if (ar > n_rows - 1) ar = n_rows - 1;
            const __bf16* abase;
            if (parents && k0 < 256)             abase = A0 + (size_t)par_s[row] * 256 + k0;
            else if (A1 != nullptr && k0 >= 256) abase = A1 + (size_t)ar * 256 + (k0 - 256);
            else                                 abase = A0 + (size_t)ar * lda + k0;
            const __bf16* ga = abase + (cs >> 1);
            char* la = (char*)As[buf] + (i * 512 + w * 64) * 16;
            __builtin_amdgcn_global_load_lds(
                (const __attribute__((address_space(1))) unsigned int*)ga,
                (__attribute__((address_space(3))) unsigned int*)la, 16, 0, 0);
        }
        // B: 128x64 = 2 issues/thread
#pragma unroll
        for (int i = 0; i < 2; ++i) {
            int f   = i * 512 + t;
            int row = f >> 3;
            int cs  = ((f & 7) * 16) ^ ((row & 7) << 4);
            const __bf16* gb = W + (size_t)(bcol + row) * ldw + k0 + (cs >> 1);
            char* lb = (char*)Bs[buf] + (i * 512 + w * 64) * 16;
            __builtin_amdgcn_global_load_lds(
                (const __attribute__((address_space(1))) unsigned int*)gb,
                (__attribute__((address_space(3))) unsigned int*)lb, 16, 0, 0);
        }
    };

    f32x4 acc[2][4] = {};
    stage(0, 0);

    for (int kt = 0; kt < kt_n; ++kt) {
        const int buf = kt & 1;
        if (kt + 1 < kt_n) {
            stage(kt + 1, buf ^ 1);
            asm volatile("s_waitcnt vmcnt(4)" ::: "memory");   // kt's 4 loads retired
        } else {
            asm volatile("s_waitcnt vmcnt(0)" ::: "memory");
        }
        PIPE_BARRIER();
#pragma unroll
        for (int ks = 0; ks < 2; ++ks) {
            bf16x8 af[2], bfv[4];
#pragma unroll
            for (int m = 0; m < 2; ++m) {
                int row = wr + m * 16 + (l & 15);
                int cb  = (ks * 64 + ((l >> 4) * 16)) ^ ((row & 7) << 4);
                af[m] = *(const bf16x8*)((const char*)As[buf] + row * 128 + cb);
            }
#pragma unroll
            for (int n = 0; n < 4; ++n) {
                int row = wc + n * 16 + (l & 15);
                int cb  = (ks * 64 + ((l >> 4) * 16)) ^ ((row & 7) << 4);
                bfv[n] = *(const bf16x8*)((const char*)Bs[buf] + row * 128 + cb);
            }
#pragma unroll
            for (int m = 0; m < 2; ++m)
#pragma unroll
                for (int n = 0; n < 4; ++n)
                    acc[m][n] = __builtin_amdgcn_mfma_f32_16x16x32_bf16(af[m], bfv[n], acc[m][n], 0, 0, 0);
        }
        PIPE_BARRIER();   // all reads of buf done before it is overwritten next iter
    }
    // epilogue: C/D mapping col = lane&15, row = (lane>>4)*4 + reg
#pragma unroll
    for (int m = 0; m < 2; ++m) {
        int r0 = brow + wr + m * 16 + ((l >> 4) * 4);
#pragma unroll
        for (int n = 0; n < 4; ++n) {
            int c = bcol + wc + n * 16 + (l & 15);
            float bv = bias[c];
#pragma unroll
            for (int i = 0; i < 4; ++i) {
                int r = r0 + i;
                if (r < n_rows) {
                    float v = acc[m][n][i] + bv;
                    __bf16 hi = (__bf16)v;
                    Cb[(size_t)r * n_cols + c] = hi;
                    if (Cl) Cl[(size_t)r * n_cols + c] = (__bf16)(v - (float)hi);
                }
            }
        }
    }
}

// ---------------------------------------------------------------- fused GRU GEMM (counted-vmcnt dbuf)
// 128x128 tile, 512 threads, 8 waves. A = [xb | sbh] (K=512 split). W = Wcat (1024 x 512):
// out-col c -> j=(c>>6)*16+(c&15), gate=(c>>4)&3.
// gates: 0 = i_r+h_r, 1 = i_z+h_z, 2 = i_n (k<256 only), 3 = h_n (k>=256 only).
// B staged unconditionally (zero blocks are real zeros in packed Wcat -> uniform 4 loads/thread);
// MFMA for the dead gate block still skipped. Flat grid (1256 = 157x8) + remap col_shift=3.
__global__ __launch_bounds__(512, 4)
void gru_gemm_kernel(const __bf16* __restrict__ A0, const __bf16* __restrict__ A1,
                     const __bf16* __restrict__ W,
                     const float* __restrict__ bias,
                     const __bf16* __restrict__ sbh, const __bf16* __restrict__ sbl,
                     float* __restrict__ X, __bf16* __restrict__ xb_next,
                     int n_rows)
{
    __shared__ __align__(16) __bf16 As[2][128 * 64];
    __shared__ __align__(16) __bf16 Bs[2][128 * 64];
    const int t = threadIdx.x;
    const int w = t >> 6;
    const int l = t & 63;
    int rb, cb_;
    xcd_remap(blockIdx.x, 157 * 8, 3, rb, cb_);
    const int brow = rb * 128;
    const int bcol = cb_ * 128;
    const int wr = (w >> 1) * 32, wc = (w & 1) * 64;

    auto stage = [&](int kt, int buf) {
        const int k0 = kt * 64;
        const __bf16* ab = (kt < 4) ? (A0 + k0) : (A1 + (k0 - 256));
        // A: 2 issues/thread
#pragma unroll
        for (int i = 0; i < 2; ++i) {
            int f   = i * 512 + t;
            int row = f >> 3;
            int cs  = ((f & 7) * 16) ^ ((row & 7) << 4);
            int ar  = brow + row; if (ar > n_rows - 1) ar = n_rows - 1;
            const __bf16* ga = ab + (size_t)ar * 256 + (cs >> 1);
            char* la = (char*)As[buf] + (i * 512 + w * 64) * 16;
            __builtin_amdgcn_global_load_lds(
                (const __attribute__((address_space(1))) unsigned int*)ga,
                (__attribute__((address_space(3))) unsigned int*)la, 16, 0, 0);
        }
        // B: 2 issues/thread (unconditional -> uniform vmcnt)
#pragma unroll
        for (int i = 0; i < 2; ++i) {
            int f   = i * 512 + t;
            int row = f >> 3;
            int cs  = ((f & 7) * 16) ^ ((row & 7) << 4);
            const __bf16* gb = W + (size_t)(bcol + row) * 512 + k0 + (cs >> 1);
            char* lb = (char*)Bs[buf] + (i * 512 + w * 64) * 16;
            __builtin_amdgcn_global_load_lds(
                (const __attribute__((address_space(1))) unsigned int*)gb,
                (__attribute__((address_space(3))) unsigned int*)lb, 16, 0, 0);
        }
    };

    f32x4 acc[2][4] = {};
    stage(0, 0);

    for (int kt = 0; kt < 8; ++kt) {
        const int buf = kt & 1;
        const int skipn = (kt < 4) ? 3 : 2;
        if (kt < 7) {
            stage(kt + 1, buf ^ 1);
            asm volatile("s_waitcnt vmcnt(4)" ::: "memory");
        } else {
            asm volatile("s_waitcnt vmcnt(0)" ::: "memory");
        }
        PIPE_BARRIER();
#pragma unroll
        for (int ks = 0; ks < 2; ++ks) {
            bf16x8 af[2], bfv[4];
#pragma unroll
            for (int m = 0; m < 2; ++m) {
                int row = wr + m * 16 + (l & 15);
                int cb  = (ks * 64 + ((l >> 4) * 16)) ^ ((row & 7) << 4);
                af[m] = *(const bf16x8*)((const char*)As[buf] + row * 128 + cb);
            }
#pragma unroll
            for (int n = 0; n < 4; ++n) {
                if (n == skipn) continue;
                int row = wc + n * 16 + (l & 15);
                int cb  = (ks * 64 + ((l >> 4) * 16)) ^ ((row & 7) << 4);
                bfv[n] = *(const bf16x8*)((const char*)Bs[buf] + row * 128 + cb);
            }
#pragma unroll
            for (int m = 0; m < 2; ++m)
#pragma unroll
                for (int n = 0; n < 4; ++n)
                    if (n != skipn)
                        acc[m][n] = __builtin_amdgcn_mfma_f32_16x16x32_bf16(af[m], bfv[n], acc[m][n], 0, 0, 0);
        }
        PIPE_BARRIER();
    }

    // GRU epilogue: each lane's 4 col-tiles (n=0..3) are the 4 gates of ONE output feature j.
    const int jb = ((bcol + wc) >> 6) * 16 + (l & 15);
    const int c0 = bcol + wc + (l & 15);
    const float b0 = bias[c0], b1 = bias[c0 + 16], b2 = bias[c0 + 32], b3 = bias[c0 + 48];
#pragma unroll
    for (int m = 0; m < 2; ++m) {
        int r0 = brow + wr + m * 16 + ((l >> 4) * 4);
#pragma unroll
        for (int i = 0; i < 4; ++i) {
            int r = r0 + i;
            if (r < n_rows) {
                float gr  = acc[m][0][i] + b0;
                float gz  = acc[m][1][i] + b1;
                float gin = acc[m][2][i] + b2;
                float ghn = acc[m][3][i] + b3;
                float rg = 1.f / (1.f + __expf(-gr));
                float zg = 1.f / (1.f + __expf(-gz));
                float a2 = gin + rg * ghn;
                float tt = __expf(-2.f * fabsf(a2));
                float ng = (1.f - tt) / (1.f + tt);
                ng = (a2 < 0.f) ? -ng : ng;
                float h = (float)sbh[(size_t)r * 256 + jb] + (float)sbl[(size_t)r * 256 + jb];
                float out = (1.f - zg) * ng + zg * h;
                if (X)       X[(size_t)r * 256 + jb] = out;
                if (xb_next) xb_next[(size_t)r * 256 + jb] = (__bf16)out;
            }
        }
    }
}

// ---------------------------------------------------------------- launch
extern "C" void kernel_launch(void* const* d_in, const int* in_sizes, int n_in,
                              void* d_out, int out_size, void* d_ws, size_t ws_size,
                              hipStream_t stream)
{
    const int*   adj   = (const int*)  d_in[0];
    const float* names = (const float*)d_in[1];
    const float* attrs = (const float*)d_in[2];
    const float* Win = (const float*)d_in[3];
    const float* bin = (const float*)d_in[4];
    const float* Wp  = (const float*)d_in[5];
    const float* bp  = (const float*)d_in[6];
    const float* Wn  = (const float*)d_in[7];
    const float* bn  = (const float*)d_in[8];
    const float* Wih = (const float*)d_in[9];
    const float* bih = (const float*)d_in[10];
    const float* Whh = (const float*)d_in[11];
    const float* bhh = (const float*)d_in[12];
    float* X = (float*)d_out;

    // workspace layout
    char* w = (char*)d_ws;
    __bf16* xinfo = (__bf16*)(w);                // N x 256 bf16   10,240,000
    __bf16* xb0   = (__bf16*)(w + 10240000);     // N x 256 bf16
    __bf16* xb1   = (__bf16*)(w + 20480000);     // N x 256 bf16
    __bf16* sbh   = (__bf16*)(w + 30720000);     // N x 256 bf16
    __bf16* sbl   = (__bf16*)(w + 40960000);     // N x 256 bf16
    __bf16* G2    = (__bf16*)(w + 51200000);     // N x 256 bf16
    __bf16* Wb    = (__bf16*)(w + 61440000);     // 720896 bf16     1,441,792
    float*  bc    = (float*) (w + 62881792);     // 1536 f32

    pack_all_kernel<<<5704, 256, 0, stream>>>(Win, bin, Wp, bp, Wn, bn, Wih, bih, Whh, bhh,
                                              names, attrs, Wb, bc, xinfo);

    // x0 = info @ Win^T + bin  -> bf16 only   (314 = 157 row-blocks x 2 col-blocks)
    gemm_bias_kernel<<<314, 512, 0, stream>>>(xinfo, nullptr, 256, nullptr, 0,
                                              Wb, 256, bc, xb0, nullptr, NN, 256, 4, 314, 1);

    __bf16* cur = xb0;
    __bf16* nxt = xb1;
    for (int d = 0; d < 3; ++d) {
        gather_avg_kernel<<<2500, 256, 0, stream>>>(adj, cur, G2);
        // summary = [x[parent] | avg] @ [Wp|Wn]^T + (bp+bn): parent half gathered in-staging,
        // output as hi/lo bf16 split
        gemm_bias_kernel<<<314, 512, 0, stream>>>(cur, G2, 256, adj, NADJ,
                                                  Wb + 65536, 512, bc + 256,
                                                  sbh, sbl, NN, 256, 8, 314, 1);
        // fused GRU: [cur|sbh] @ Wcat^T, epilogue computes gates + output   (1256 = 157 x 8)
        gru_gemm_kernel<<<1256, 512, 0, stream>>>(cur, sbh, Wb + 196608, bc + 512,
                                                  sbh, sbl, (d == 2) ? X : nullptr,
                                                  (d < 2) ? nxt : nullptr, NN);
        __bf16* tmp = cur; cur = nxt; nxt = tmp;
    }
}